// Round 6
// baseline (268.153 us; speedup 1.0000x reference)
//
#include <hip/hip_runtime.h>
#include <math.h>

#define SCALE 0.17677669529663687f   // 32^-0.5

typedef float f32x4 __attribute__((ext_vector_type(4)));
typedef short s16x8 __attribute__((ext_vector_type(8)));

__device__ __forceinline__ unsigned short f2bf(float f) {
    unsigned int u = __float_as_uint(f);
    u += 0x7fffu + ((u >> 16) & 1u);          // RNE
    return (unsigned short)(u >> 16);
}
__device__ __forceinline__ unsigned int pk2(float a, float b) {
    return (unsigned int)f2bf(a) | ((unsigned int)f2bf(b) << 16);
}

// ---------------------------------------------------------------------------
// K0: one-time prep.
//  - wqT[c][k] (288x96) bf16, Q-scale folded into first 96 cols
//  - woT[c][k] (96x96) bf16
//  - bias_exp[3][49][64] f32: rel-pos bias expanded dense so attention C-init
//    is one dwordx4 load. kt in [49,64) = 0 (masked post-MFMA).
// ---------------------------------------------------------------------------
__global__ void k_prep(const float* __restrict__ wq, const float* __restrict__ wo,
                       const float* __restrict__ rel_pos,
                       unsigned short* __restrict__ wqT, unsigned short* __restrict__ woT,
                       float* __restrict__ bias_exp) {
    int i = blockIdx.x * 256 + threadIdx.x;
    if (i < 27648) {
        int c = i / 96, k = i - c * 96;
        float w = wq[k * 288 + c];
        if (c < 96) w *= SCALE;                 // pre-scale q columns
        wqT[i] = f2bf(w);
    } else if (i < 36864) {
        int t = i - 27648;
        int c = t / 96, k = t - c * 96;
        woT[t] = f2bf(wo[k * 96 + c]);
    } else if (i < 36864 + 3 * 49 * 64) {
        int t = i - 36864;
        int g = t / 3136, r = t - g * 3136;
        int q = r >> 6, kt = r & 63;
        float v = 0.f;
        if (kt < 49) {
            int qp = q / 7, qq = q - qp * 7;
            int kp = kt / 7, kq = kt - kp * 7;
            v = rel_pos[g * 169 + (qp - kp + 6) * 13 + (qq - kq + 6)];
        }
        bias_exp[t] = v;
    }
}

// ---------------------------------------------------------------------------
// K1: fused per-window kernel, 192 threads (3 waves), wave g = head g
// end-to-end. Round-6: V^T LDS buffer ELIMINATED via in-register cross-lane
// redistribution (round-5 structure otherwise unchanged):
//   v-GEMM leaves lane (ln,kg') holding V[d=16tc+ln][tok 16tt'+4kg'..+3];
//   the PV A-fragment needs lane (ln,kg) to hold V^T[d=16td+ln][toks
//   32ks+8kg..+7] -- same ln, kg-permuted: producer packs each granule to
//   2 bf16 dwords, consumer rebuilds via 32 ds_bpermute + 16 cndmask
//   (bit-identical to the old LDS round-trip).
// LDS 21,168 B (alloc 21,504) -> 7 blocks/CU = 21 waves/CU (was 4 blocks /
// 12 waves at 35,328 B). Single barrier (pre-out-proj) retained.
// ---------------------------------------------------------------------------
#define USTR  72   // U row stride (shorts): 144 B, 16B-aligned, 36 dwords (4 mod 32)

__global__ __launch_bounds__(192, 5) void k_fused(
        const float* __restrict__ x,
        const unsigned short* __restrict__ wqT,
        const float* __restrict__ b_qkv,
        const float* __restrict__ bias_exp,
        const unsigned short* __restrict__ woT,
        const float* __restrict__ b_out,
        float* __restrict__ out) {
    __shared__ unsigned short s_u[3][49 * USTR];  // 21168 B: per-head q|k -> P -> ao

    const int tid  = threadIdx.x;
    const int g    = tid >> 6;         // wave index == head index (0..2)
    const int lane = tid & 63;
    const int ln   = lane & 15;
    const int kg   = lane >> 4;

    const int win = blockIdx.x;
    const int ww = win & 7, hh = (win >> 3) & 7, b = win >> 6;
    const size_t base = (size_t)b * 3136;

    unsigned short* const U = s_u[g];

    // ---- x fragments: direct global->reg (fp32 -> bf16, software RNE) ----
    s16x8 xf[4][3];
#pragma unroll
    for (int t = 0; t < 4; ++t) {
        int tok = 16 * t + ln; if (tok > 48) tok = 48;
        const int p = (tok * 37) >> 8;             // tok/7 for tok<=48
        const int q = tok - p * 7;
        const float* xr = x + (base + (p * 8 + hh) * 56 + q * 8 + ww) * 96;
#pragma unroll
        for (int ks = 0; ks < 3; ++ks) {
            const float4 lo = *(const float4*)(xr + 32 * ks + 8 * kg);
            const float4 hi = *(const float4*)(xr + 32 * ks + 8 * kg + 4);
            uint4 u;
            u.x = pk2(lo.x, lo.y); u.y = pk2(lo.z, lo.w);
            u.z = pk2(hi.x, hi.y); u.w = pk2(hi.z, hi.w);
            xf[t][ks] = *(s16x8*)&u;
        }
    }

    __builtin_amdgcn_s_setprio(1);                 // favor compute-phase waves

    // ---- Phase B: QKV GEMM for head g ----
    // q,k swapped: D[d][tok] -> b64 writes into [tok][d]; bias as C-init.
#pragma unroll
    for (int part = 0; part < 2; ++part) {           // 0:q (pre-scaled W), 1:k
#pragma unroll
        for (int tc = 0; tc < 2; ++tc) {
            const int col = part * 96 + g * 32 + 16 * tc + ln;
            s16x8 wf[3];
#pragma unroll
            for (int ks = 0; ks < 3; ++ks)
                wf[ks] = *(const s16x8*)(wqT + (size_t)col * 96 + 32 * ks + 8 * kg);
            const float4 bs = *(const float4*)(b_qkv + part * 96 + g * 32 + 16 * tc + 4 * kg);
            const float bm = part ? 1.0f : SCALE;
#pragma unroll
            for (int tt = 0; tt < 4; ++tt) {
                f32x4 a = {bs.x * bm, bs.y * bm, bs.z * bm, bs.w * bm};
#pragma unroll
                for (int ks = 0; ks < 3; ++ks)
                    a = __builtin_amdgcn_mfma_f32_16x16x32_bf16(wf[ks], xf[tt][ks], a, 0, 0, 0);
                if (tt < 3 || ln == 0) {             // token rows < 49 only
                    uint2 u; u.x = pk2(a[0], a[1]); u.y = pk2(a[2], a[3]);
                    *(uint2*)(U + (16 * tt + ln) * USTR + part * 40 + 16 * tc + 4 * kg) = u;
                }
            }
        }
    }
    // v non-swapped: D[tok][d] -> lane (ln,kg) holds V[d=16tc+ln][16tt+4kg..+3];
    // pack each granule to 2 bf16 dwords (registers, no LDS).
    int vpk01[2][4], vpk23[2][4];
#pragma unroll
    for (int tc = 0; tc < 2; ++tc) {
        const int col = 192 + g * 32 + 16 * tc + ln;
        s16x8 wf[3];
#pragma unroll
        for (int ks = 0; ks < 3; ++ks)
            wf[ks] = *(const s16x8*)(wqT + (size_t)col * 96 + 32 * ks + 8 * kg);
        const float bv = b_qkv[col];
#pragma unroll
        for (int tt = 0; tt < 4; ++tt) {
            f32x4 a = {bv, bv, bv, bv};
#pragma unroll
            for (int ks = 0; ks < 3; ++ks)
                a = __builtin_amdgcn_mfma_f32_16x16x32_bf16(xf[tt][ks], wf[ks], a, 0, 0, 0);
            vpk01[tc][tt] = (int)pk2(a[0], a[1]);
            vpk23[tc][tt] = (int)pk2(a[2], a[3]);
        }
    }
    // V^T fragments via cross-lane redistribution:
    // vf[td][ks](ln,kg)[e] = V^T[16td+ln][32ks+8kg+e], e=0..7.
    // Sources: lanes 16*kgp+ln, kgp in {2(kg&1), 2(kg&1)+1}; producer register
    // tt' = 2ks+(kg>>1) (lane-varying -> bpermute both, cndmask select).
    s16x8 vf[2][2];
    {
        const int addrA = 4 * (32 * (kg & 1) + ln);   // lane 16*2(kg&1)+ln
        const int addrB = addrA + 64;                 // lane +16
        const bool hi = (kg >> 1) != 0;
#pragma unroll
        for (int td = 0; td < 2; ++td)
#pragma unroll
            for (int ks = 0; ks < 2; ++ks) {
                const int d0a = __builtin_amdgcn_ds_bpermute(addrA, vpk01[td][2 * ks]);
                const int d0b = __builtin_amdgcn_ds_bpermute(addrA, vpk01[td][2 * ks + 1]);
                const int d1a = __builtin_amdgcn_ds_bpermute(addrA, vpk23[td][2 * ks]);
                const int d1b = __builtin_amdgcn_ds_bpermute(addrA, vpk23[td][2 * ks + 1]);
                const int d2a = __builtin_amdgcn_ds_bpermute(addrB, vpk01[td][2 * ks]);
                const int d2b = __builtin_amdgcn_ds_bpermute(addrB, vpk01[td][2 * ks + 1]);
                const int d3a = __builtin_amdgcn_ds_bpermute(addrB, vpk23[td][2 * ks]);
                const int d3b = __builtin_amdgcn_ds_bpermute(addrB, vpk23[td][2 * ks + 1]);
                uint4 u;
                u.x = (unsigned)(hi ? d0b : d0a);
                u.y = (unsigned)(hi ? d1b : d1a);
                u.z = (unsigned)(hi ? d2b : d2a);
                u.w = (unsigned)(hi ? d3b : d3a);
                vf[td][ks] = *(s16x8*)&u;
            }
    }

    // ---- Phase C: attention for head g (same-wave DS ordering, no barriers) ----
    s16x8 qf[4], kf[4];
#pragma unroll
    for (int t = 0; t < 4; ++t) {
        int tok = 16 * t + ln; if (tok > 48) tok = 48;
        qf[t] = *(const s16x8*)(U + tok * USTR + 8 * kg);
        kf[t] = *(const s16x8*)(U + tok * USTR + 40 + 8 * kg);
    }
    // Swapped QK^T: S^T[kt][q]; dense bias row as dwordx4 C-init.
    const int qrow[4] = { ln, 16 + ln, 32 + ln, 48 };
    f32x4 sacc[4][4];                                // [tk][tq]
#pragma unroll
    for (int tq = 0; tq < 4; ++tq) {
        const float* brow = bias_exp + (g * 49 + qrow[tq]) * 64;
#pragma unroll
        for (int tk = 0; tk < 4; ++tk) {
            const float4 bb = *(const float4*)(brow + 16 * tk + 4 * kg);
            f32x4 c = {bb.x, bb.y, bb.z, bb.w};
            sacc[tk][tq] = __builtin_amdgcn_mfma_f32_16x16x32_bf16(kf[tk], qf[tq], c, 0, 0, 0);
        }
    }
    // mask kt >= 49 (tile 3: kt = 48 + 4kg + r)
#pragma unroll
    for (int tq = 0; tq < 4; ++tq) {
        sacc[3][tq][1] = -3e38f; sacc[3][tq][2] = -3e38f; sacc[3][tq][3] = -3e38f;
        if (kg) sacc[3][tq][0] = -3e38f;
    }
    // softmax per q (r and tk in-lane, kg cross-lane)
#pragma unroll
    for (int tq = 0; tq < 4; ++tq) {
        float m0 = fmaxf(fmaxf(sacc[0][tq][0], sacc[0][tq][1]), fmaxf(sacc[0][tq][2], sacc[0][tq][3]));
        float m1 = fmaxf(fmaxf(sacc[1][tq][0], sacc[1][tq][1]), fmaxf(sacc[1][tq][2], sacc[1][tq][3]));
        float m2 = fmaxf(fmaxf(sacc[2][tq][0], sacc[2][tq][1]), fmaxf(sacc[2][tq][2], sacc[2][tq][3]));
        float m3 = fmaxf(fmaxf(sacc[3][tq][0], sacc[3][tq][1]), fmaxf(sacc[3][tq][2], sacc[3][tq][3]));
        float m = fmaxf(fmaxf(m0, m1), fmaxf(m2, m3));
        m = fmaxf(m, __shfl_xor(m, 16));
        m = fmaxf(m, __shfl_xor(m, 32));
        float s = 0.f;
#pragma unroll
        for (int tk = 0; tk < 4; ++tk)
#pragma unroll
            for (int r = 0; r < 4; ++r) {
                const float e = __expf(sacc[tk][tq][r] - m);
                sacc[tk][tq][r] = e; s += e;
            }
        s += __shfl_xor(s, 16);
        s += __shfl_xor(s, 32);
        const float inv = 1.0f / s;                  // normalize P pre-store
        if (tq < 3 || ln == 0) {
#pragma unroll
            for (int tk = 0; tk < 4; ++tk) {
                uint2 u;
                u.x = pk2(sacc[tk][tq][0] * inv, sacc[tk][tq][1] * inv);
                u.y = pk2(sacc[tk][tq][2] * inv, sacc[tk][tq][3] * inv);
                *(uint2*)(U + (16 * tq + ln) * USTR + 16 * tk + 4 * kg) = u;
            }
        }
    }

    // PV: O^T[d][q] -> b64 ao writes into U cols [0,32) (q|k and P dead)
    s16x8 pf[4][2];
#pragma unroll
    for (int tq = 0; tq < 4; ++tq) {
        int pr = 16 * tq + ln; if (pr > 48) pr = 48;
#pragma unroll
        for (int ks = 0; ks < 2; ++ks)
            pf[tq][ks] = *(const s16x8*)(U + pr * USTR + 32 * ks + 8 * kg);
    }
#pragma unroll
    for (int td = 0; td < 2; ++td)
#pragma unroll
        for (int tq = 0; tq < 4; ++tq) {
            f32x4 a = {0.f, 0.f, 0.f, 0.f};
            a = __builtin_amdgcn_mfma_f32_16x16x32_bf16(vf[td][0], pf[tq][0], a, 0, 0, 0);
            a = __builtin_amdgcn_mfma_f32_16x16x32_bf16(vf[td][1], pf[tq][1], a, 0, 0, 0);
            const int q = 16 * tq + ln;
            if (q < 49) {
                uint2 u; u.x = pk2(a[0], a[1]); u.y = pk2(a[2], a[3]);
                *(uint2*)(U + q * USTR + 16 * td + 4 * kg) = u;
            }
        }
    __builtin_amdgcn_s_setprio(0);
    __syncthreads();                                 // the only barrier: ao complete

    // ---- Phase D: out-proj; wave g owns out-tiles {2g, 2g+1}:
    // 128 B contiguous per token per wave ----
    s16x8 af[4][3];
#pragma unroll
    for (int tt = 0; tt < 4; ++tt) {
        int tok = 16 * tt + ln; if (tok > 48) tok = 48;
#pragma unroll
        for (int ks = 0; ks < 3; ++ks)
            af[tt][ks] = *(const s16x8*)(s_u[ks] + tok * USTR + 8 * kg);
    }
#pragma unroll
    for (int j = 0; j < 2; ++j) {
        const int tc = 2 * g + j;
        s16x8 wf[3];
#pragma unroll
        for (int ks = 0; ks < 3; ++ks)
            wf[ks] = *(const s16x8*)(woT + (size_t)(16 * tc + ln) * 96 + 32 * ks + 8 * kg);
        const float4 bs = *(const float4*)(b_out + 16 * tc + 4 * kg);
#pragma unroll
        for (int tt = 0; tt < 4; ++tt) {
            f32x4 a = {bs.x, bs.y, bs.z, bs.w};      // bias as C-init
#pragma unroll
            for (int ks = 0; ks < 3; ++ks)
                a = __builtin_amdgcn_mfma_f32_16x16x32_bf16(wf[ks], af[tt][ks], a, 0, 0, 0);
            const int tok = 16 * tt + ln;
            if (tok < 49) {
                const int p = (tok * 37) >> 8;       // tok/7 for tok<=48
                const int q = tok - p * 7;
                float4 o; o.x = a[0]; o.y = a[1]; o.z = a[2]; o.w = a[3];
                *(float4*)(out + (base + (p * 8 + hh) * 56 + q * 8 + ww) * 96 + 16 * tc + 4 * kg) = o;
            }
        }
    }
}

// ---------------------------------------------------------------------------
// Fallback (round-1 fp32 monolith) if workspace is too small.
// ---------------------------------------------------------------------------
__global__ void winattn_fp32(const float* __restrict__ x,
                             const float* __restrict__ w_qkv,
                             const float* __restrict__ b_qkv,
                             const float* __restrict__ rel_pos,
                             const float* __restrict__ w_out,
                             const float* __restrict__ b_out,
                             float* __restrict__ out) {
    __shared__ float s_x[49][96];
    __shared__ float s_qkv[49][288];
    __shared__ float s_rel[3 * 169];
    const int t = threadIdx.x;
    const int blk = blockIdx.x;
    const int ww = blk & 7, hh = (blk >> 3) & 7, b = blk >> 6;
    for (int i = t; i < 3 * 169; i += 256) s_rel[i] = rel_pos[i];
    const float* xb = x + (size_t)b * 56 * 56 * 96;
    for (int i = t; i < 49 * 24; i += 256) {
        int tok = i / 24, ch4 = i % 24, p = tok / 7, q = tok % 7;
        float4 v = *(const float4*)(xb + (((p * 8 + hh) * 56) + (q * 8 + ww)) * 96 + ch4 * 4);
        *(float4*)(&s_x[tok][ch4 * 4]) = v;
    }
    __syncthreads();
    for (int u = t; u < 504; u += 256) {
        int cg = u % 72, rg = u / 72, col = cg * 4, r0 = rg * 7;
        float4 bq = *(const float4*)(b_qkv + col);
        float acc[7][4];
#pragma unroll
        for (int r = 0; r < 7; ++r) { acc[r][0]=bq.x; acc[r][1]=bq.y; acc[r][2]=bq.z; acc[r][3]=bq.w; }
        for (int k = 0; k < 96; k += 4) {
            float4 w0 = *(const float4*)(w_qkv + (size_t)(k+0)*288 + col);
            float4 w1 = *(const float4*)(w_qkv + (size_t)(k+1)*288 + col);
            float4 w2 = *(const float4*)(w_qkv + (size_t)(k+2)*288 + col);
            float4 w3 = *(const float4*)(w_qkv + (size_t)(k+3)*288 + col);
#pragma unroll
            for (int r = 0; r < 7; ++r) {
                float4 xv = *(const float4*)(&s_x[r0+r][k]);
                acc[r][0] += xv.x*w0.x + xv.y*w1.x + xv.z*w2.x + xv.w*w3.x;
                acc[r][1] += xv.x*w0.y + xv.y*w1.y + xv.z*w2.y + xv.w*w3.y;
                acc[r][2] += xv.x*w0.z + xv.y*w1.z + xv.z*w2.z + xv.w*w3.z;
                acc[r][3] += xv.x*w0.w + xv.y*w1.w + xv.z*w2.w + xv.w*w3.w;
            }
        }
#pragma unroll
        for (int r = 0; r < 7; ++r)
            *(float4*)(&s_qkv[r0+r][col]) = make_float4(acc[r][0],acc[r][1],acc[r][2],acc[r][3]);
    }
    __syncthreads();
    if (t < 147) {
        const int g = t / 49, qi = t - g * 49, pi = qi / 7, qq = qi - pi * 7;
        float qreg[32];
#pragma unroll
        for (int d = 0; d < 32; d += 4) {
            float4 v = *(const float4*)(&s_qkv[qi][g*32 + d]);
            qreg[d]=v.x*SCALE; qreg[d+1]=v.y*SCALE; qreg[d+2]=v.z*SCALE; qreg[d+3]=v.w*SCALE;
        }
        float sim[49]; float m = -1e30f;
        for (int j = 0; j < 49; ++j) {
            float a = 0.f;
            const float* kr = &s_qkv[j][96 + g*32];
#pragma unroll
            for (int d = 0; d < 32; d += 4) {
                float4 kv = *(const float4*)(kr + d);
                a += qreg[d]*kv.x + qreg[d+1]*kv.y + qreg[d+2]*kv.z + qreg[d+3]*kv.w;
            }
            int pj = j / 7, qj = j % 7;
            a += s_rel[g*169 + (pi-pj+6)*13 + (qq-qj+6)];
            sim[j] = a; m = fmaxf(m, a);
        }
        float s = 0.f;
        for (int j = 0; j < 49; ++j) { float e = __expf(sim[j]-m); sim[j]=e; s+=e; }
        float inv = 1.f/s;
        float o[32];
#pragma unroll
        for (int d = 0; d < 32; ++d) o[d] = 0.f;
        for (int j = 0; j < 49; ++j) {
            float p = sim[j];
            const float* vr = &s_qkv[j][192 + g*32];
#pragma unroll
            for (int d = 0; d < 32; d += 4) {
                float4 vv = *(const float4*)(vr + d);
                o[d] += p*vv.x; o[d+1] += p*vv.y; o[d+2] += p*vv.z; o[d+3] += p*vv.w;
            }
        }
#pragma unroll
        for (int d = 0; d < 32; d += 4)
            *(float4*)(&s_x[qi][g*32 + d]) = make_float4(o[d]*inv, o[d+1]*inv, o[d+2]*inv, o[d+3]*inv);
    }
    __syncthreads();
    for (int u = t; u < 336; u += 256) {
        int cg = u % 48, rg = u / 48, col = cg * 2, r0 = rg * 7;
        float b0 = b_out[col], b1 = b_out[col+1];
        float acc[7][2];
#pragma unroll
        for (int r = 0; r < 7; ++r) { acc[r][0]=b0; acc[r][1]=b1; }
        for (int k = 0; k < 96; k += 4) {
            float2 w0 = *(const float2*)(w_out + (size_t)(k+0)*96 + col);
            float2 w1 = *(const float2*)(w_out + (size_t)(k+1)*96 + col);
            float2 w2 = *(const float2*)(w_out + (size_t)(k+2)*96 + col);
            float2 w3 = *(const float2*)(w_out + (size_t)(k+3)*96 + col);
#pragma unroll
            for (int r = 0; r < 7; ++r) {
                float4 xv = *(const float4*)(&s_x[r0+r][k]);
                acc[r][0] += xv.x*w0.x + xv.y*w1.x + xv.z*w2.x + xv.w*w3.x;
                acc[r][1] += xv.x*w0.y + xv.y*w1.y + xv.z*w2.y + xv.w*w3.y;
            }
        }
#pragma unroll
        for (int r = 0; r < 7; ++r)
            *(float2*)(out + (size_t)(((b*56 + rg*8 + hh)*56) + r*8 + ww)*96 + col) =
                make_float2(acc[r][0], acc[r][1]);
    }
}

extern "C" void kernel_launch(void* const* d_in, const int* in_sizes, int n_in,
                              void* d_out, int out_size, void* d_ws, size_t ws_size,
                              hipStream_t stream) {
    const float* x       = (const float*)d_in[0];
    const float* w_qkv   = (const float*)d_in[1];
    const float* b_qkv   = (const float*)d_in[2];
    const float* rel_pos = (const float*)d_in[3];
    const float* w_out   = (const float*)d_in[4];
    const float* b_out   = (const float*)d_in[5];
    float* out = (float*)d_out;

    const size_t WQT_BYTES  = (size_t)288 * 96 * 2;     // 55,296
    const size_t WOT_BYTES  = (size_t)96 * 96 * 2;      // 18,432
    const size_t BIAS_BYTES = (size_t)3 * 49 * 64 * 4;  // 37,632

    if (ws_size >= WQT_BYTES + WOT_BYTES + BIAS_BYTES) {
        unsigned short* wqT = (unsigned short*)d_ws;
        unsigned short* woT = (unsigned short*)((char*)d_ws + WQT_BYTES);
        float* bias_exp     = (float*)((char*)d_ws + WQT_BYTES + WOT_BYTES);
        hipLaunchKernelGGL(k_prep,  dim3(181),  dim3(256), 0, stream,
                           w_qkv, w_out, rel_pos, wqT, woT, bias_exp);
        hipLaunchKernelGGL(k_fused, dim3(4096), dim3(192), 0, stream,
                           x, wqT, b_qkv, bias_exp, woT, b_out, out);
    } else {
        hipLaunchKernelGGL(winattn_fp32, dim3(4096), dim3(256), 0, stream,
                           x, w_qkv, b_qkv, rel_pos, w_out, b_out, out);
    }
}

// Round 7
// 199.976 us; speedup vs baseline: 1.3409x; 1.3409x over previous
//
#include <hip/hip_runtime.h>
#include <math.h>

#define SCALE 0.17677669529663687f   // 32^-0.5

typedef float f32x4 __attribute__((ext_vector_type(4)));
typedef short s16x8 __attribute__((ext_vector_type(8)));

__device__ __forceinline__ unsigned short f2bf(float f) {
    unsigned int u = __float_as_uint(f);
    u += 0x7fffu + ((u >> 16) & 1u);          // RNE
    return (unsigned short)(u >> 16);
}
__device__ __forceinline__ unsigned int pk2(float a, float b) {
    return (unsigned int)f2bf(a) | ((unsigned int)f2bf(b) << 16);
}

// ---------------------------------------------------------------------------
// K0: one-time prep.
//  - wqT[c][k] (288x96) bf16, Q-scale folded into first 96 cols
//  - woT[c][k] (96x96) bf16
//  - bias_exp[3][49][64] f32: rel-pos bias expanded dense so attention C-init
//    is one dwordx4 load. kt in [49,64) = 0 (masked post-MFMA).
// ---------------------------------------------------------------------------
__global__ void k_prep(const float* __restrict__ wq, const float* __restrict__ wo,
                       const float* __restrict__ rel_pos,
                       unsigned short* __restrict__ wqT, unsigned short* __restrict__ woT,
                       float* __restrict__ bias_exp) {
    int i = blockIdx.x * 256 + threadIdx.x;
    if (i < 27648) {
        int c = i / 96, k = i - c * 96;
        float w = wq[k * 288 + c];
        if (c < 96) w *= SCALE;                 // pre-scale q columns
        wqT[i] = f2bf(w);
    } else if (i < 36864) {
        int t = i - 27648;
        int c = t / 96, k = t - c * 96;
        woT[t] = f2bf(wo[k * 96 + c]);
    } else if (i < 36864 + 3 * 49 * 64) {
        int t = i - 36864;
        int g = t / 3136, r = t - g * 3136;
        int q = r >> 6, kt = r & 63;
        float v = 0.f;
        if (kt < 49) {
            int qp = q / 7, qq = q - qp * 7;
            int kp = kt / 7, kq = kt - kp * 7;
            v = rel_pos[g * 169 + (qp - kp + 6) * 13 + (qq - kq + 6)];
        }
        bias_exp[t] = v;
    }
}

// ---------------------------------------------------------------------------
// K1: fused per-window kernel, 192 threads (3 waves), wave g = head g
// end-to-end. Round-7 = round-6 (V^T-in-registers via ds_bpermute, single
// barrier, 21.5 KB LDS) with the SPILL REMOVED:
//   - __launch_bounds__(192,4): round-6's (192,5) squeezed the allocator to
//     48 VGPR vs the code's ~96 natural -> scratch spills through global
//     (FETCH 38->117 MB, WRITE 77->236 MB, dur 103->164 us). Cap 128 now.
//   - softmax processed in two tq-halves (sacc[4][2], proven R1/R2) to lower
//     natural peak pressure toward the 102-VGPR 5-waves/EU threshold.
// LDS 21,168 B (alloc 21,504) -> up to 7 blocks/CU; occupancy now set by
// real VGPR count, not a starved allocator.
// ---------------------------------------------------------------------------
#define USTR  72   // U row stride (shorts): 144 B, 16B-aligned, 36 dwords (4 mod 32)

__global__ __launch_bounds__(192, 4) void k_fused(
        const float* __restrict__ x,
        const unsigned short* __restrict__ wqT,
        const float* __restrict__ b_qkv,
        const float* __restrict__ bias_exp,
        const unsigned short* __restrict__ woT,
        const float* __restrict__ b_out,
        float* __restrict__ out) {
    __shared__ unsigned short s_u[3][49 * USTR];  // 21168 B: per-head q|k -> P -> ao

    const int tid  = threadIdx.x;
    const int g    = tid >> 6;         // wave index == head index (0..2)
    const int lane = tid & 63;
    const int ln   = lane & 15;
    const int kg   = lane >> 4;

    const int win = blockIdx.x;
    const int ww = win & 7, hh = (win >> 3) & 7, b = win >> 6;
    const size_t base = (size_t)b * 3136;

    unsigned short* const U = s_u[g];

    // ---- x fragments: direct global->reg (fp32 -> bf16, software RNE) ----
    s16x8 xf[4][3];
#pragma unroll
    for (int t = 0; t < 4; ++t) {
        int tok = 16 * t + ln; if (tok > 48) tok = 48;
        const int p = (tok * 37) >> 8;             // tok/7 for tok<=48
        const int q = tok - p * 7;
        const float* xr = x + (base + (p * 8 + hh) * 56 + q * 8 + ww) * 96;
#pragma unroll
        for (int ks = 0; ks < 3; ++ks) {
            const float4 lo = *(const float4*)(xr + 32 * ks + 8 * kg);
            const float4 hi = *(const float4*)(xr + 32 * ks + 8 * kg + 4);
            uint4 u;
            u.x = pk2(lo.x, lo.y); u.y = pk2(lo.z, lo.w);
            u.z = pk2(hi.x, hi.y); u.w = pk2(hi.z, hi.w);
            xf[t][ks] = *(s16x8*)&u;
        }
    }

    __builtin_amdgcn_s_setprio(1);                 // favor compute-phase waves

    // ---- Phase B: QKV GEMM for head g ----
    // q,k swapped: D[d][tok] -> b64 writes into [tok][d]; bias as C-init.
#pragma unroll
    for (int part = 0; part < 2; ++part) {           // 0:q (pre-scaled W), 1:k
#pragma unroll
        for (int tc = 0; tc < 2; ++tc) {
            const int col = part * 96 + g * 32 + 16 * tc + ln;
            s16x8 wf[3];
#pragma unroll
            for (int ks = 0; ks < 3; ++ks)
                wf[ks] = *(const s16x8*)(wqT + (size_t)col * 96 + 32 * ks + 8 * kg);
            const float4 bs = *(const float4*)(b_qkv + part * 96 + g * 32 + 16 * tc + 4 * kg);
            const float bm = part ? 1.0f : SCALE;
#pragma unroll
            for (int tt = 0; tt < 4; ++tt) {
                f32x4 a = {bs.x * bm, bs.y * bm, bs.z * bm, bs.w * bm};
#pragma unroll
                for (int ks = 0; ks < 3; ++ks)
                    a = __builtin_amdgcn_mfma_f32_16x16x32_bf16(wf[ks], xf[tt][ks], a, 0, 0, 0);
                if (tt < 3 || ln == 0) {             // token rows < 49 only
                    uint2 u; u.x = pk2(a[0], a[1]); u.y = pk2(a[2], a[3]);
                    *(uint2*)(U + (16 * tt + ln) * USTR + part * 40 + 16 * tc + 4 * kg) = u;
                }
            }
        }
    }
    // v non-swapped: D[tok][d] -> lane (ln,kg) holds V[d=16tc+ln][16tt+4kg..+3];
    // pack each granule to 2 bf16 dwords (registers, no LDS).
    int vpk01[2][4], vpk23[2][4];
#pragma unroll
    for (int tc = 0; tc < 2; ++tc) {
        const int col = 192 + g * 32 + 16 * tc + ln;
        s16x8 wf[3];
#pragma unroll
        for (int ks = 0; ks < 3; ++ks)
            wf[ks] = *(const s16x8*)(wqT + (size_t)col * 96 + 32 * ks + 8 * kg);
        const float bv = b_qkv[col];
#pragma unroll
        for (int tt = 0; tt < 4; ++tt) {
            f32x4 a = {bv, bv, bv, bv};
#pragma unroll
            for (int ks = 0; ks < 3; ++ks)
                a = __builtin_amdgcn_mfma_f32_16x16x32_bf16(xf[tt][ks], wf[ks], a, 0, 0, 0);
            vpk01[tc][tt] = (int)pk2(a[0], a[1]);
            vpk23[tc][tt] = (int)pk2(a[2], a[3]);
        }
    }
    // V^T fragments via cross-lane redistribution:
    // vf[td][ks](ln,kg)[e] = V^T[16td+ln][32ks+8kg+e], e=0..7.
    // Sources: lanes 16*kgp+ln, kgp in {2(kg&1), 2(kg&1)+1}; producer register
    // tt' = 2ks+(kg>>1) (lane-varying -> bpermute both, cndmask select).
    s16x8 vf[2][2];
    {
        const int addrA = 4 * (32 * (kg & 1) + ln);   // lane 16*2(kg&1)+ln
        const int addrB = addrA + 64;                 // lane +16
        const bool hi = (kg >> 1) != 0;
#pragma unroll
        for (int td = 0; td < 2; ++td)
#pragma unroll
            for (int ks = 0; ks < 2; ++ks) {
                const int d0a = __builtin_amdgcn_ds_bpermute(addrA, vpk01[td][2 * ks]);
                const int d0b = __builtin_amdgcn_ds_bpermute(addrA, vpk01[td][2 * ks + 1]);
                const int d1a = __builtin_amdgcn_ds_bpermute(addrA, vpk23[td][2 * ks]);
                const int d1b = __builtin_amdgcn_ds_bpermute(addrA, vpk23[td][2 * ks + 1]);
                const int d2a = __builtin_amdgcn_ds_bpermute(addrB, vpk01[td][2 * ks]);
                const int d2b = __builtin_amdgcn_ds_bpermute(addrB, vpk01[td][2 * ks + 1]);
                const int d3a = __builtin_amdgcn_ds_bpermute(addrB, vpk23[td][2 * ks]);
                const int d3b = __builtin_amdgcn_ds_bpermute(addrB, vpk23[td][2 * ks + 1]);
                uint4 u;
                u.x = (unsigned)(hi ? d0b : d0a);
                u.y = (unsigned)(hi ? d1b : d1a);
                u.z = (unsigned)(hi ? d2b : d2a);
                u.w = (unsigned)(hi ? d3b : d3a);
                vf[td][ks] = *(s16x8*)&u;
            }
    }

    // ---- Phase C: attention for head g (same-wave DS ordering, no barriers) ----
    s16x8 qf[4], kf[4];
#pragma unroll
    for (int t = 0; t < 4; ++t) {
        int tok = 16 * t + ln; if (tok > 48) tok = 48;
        qf[t] = *(const s16x8*)(U + tok * USTR + 8 * kg);
        kf[t] = *(const s16x8*)(U + tok * USTR + 40 + 8 * kg);
    }
    // Swapped QK^T in two tq-halves (sacc[4][2] = 32 VGPR peak, not 64).
#pragma unroll
    for (int th = 0; th < 2; ++th) {
        f32x4 sacc[4][2];
#pragma unroll
        for (int j = 0; j < 2; ++j) {
            const int tq = 2 * th + j;
            int qr = 16 * tq + ln; if (qr > 48) qr = 48;
            const float* brow = bias_exp + (g * 49 + qr) * 64;
#pragma unroll
            for (int tk = 0; tk < 4; ++tk) {
                const float4 bb = *(const float4*)(brow + 16 * tk + 4 * kg);
                f32x4 c = {bb.x, bb.y, bb.z, bb.w};
                sacc[tk][j] = __builtin_amdgcn_mfma_f32_16x16x32_bf16(kf[tk], qf[tq], c, 0, 0, 0);
            }
        }
        // mask kt >= 49 (tile 3: kt = 48 + 4kg + r)
#pragma unroll
        for (int j = 0; j < 2; ++j) {
            sacc[3][j][1] = -3e38f; sacc[3][j][2] = -3e38f; sacc[3][j][3] = -3e38f;
            if (kg) sacc[3][j][0] = -3e38f;
        }
        // softmax per q (r and tk in-lane, kg cross-lane)
#pragma unroll
        for (int j = 0; j < 2; ++j) {
            const int tq = 2 * th + j;
            float m0 = fmaxf(fmaxf(sacc[0][j][0], sacc[0][j][1]), fmaxf(sacc[0][j][2], sacc[0][j][3]));
            float m1 = fmaxf(fmaxf(sacc[1][j][0], sacc[1][j][1]), fmaxf(sacc[1][j][2], sacc[1][j][3]));
            float m2 = fmaxf(fmaxf(sacc[2][j][0], sacc[2][j][1]), fmaxf(sacc[2][j][2], sacc[2][j][3]));
            float m3 = fmaxf(fmaxf(sacc[3][j][0], sacc[3][j][1]), fmaxf(sacc[3][j][2], sacc[3][j][3]));
            float m = fmaxf(fmaxf(m0, m1), fmaxf(m2, m3));
            m = fmaxf(m, __shfl_xor(m, 16));
            m = fmaxf(m, __shfl_xor(m, 32));
            float s = 0.f;
#pragma unroll
            for (int tk = 0; tk < 4; ++tk)
#pragma unroll
                for (int r = 0; r < 4; ++r) {
                    const float e = __expf(sacc[tk][j][r] - m);
                    sacc[tk][j][r] = e; s += e;
                }
            s += __shfl_xor(s, 16);
            s += __shfl_xor(s, 32);
            const float inv = 1.0f / s;              // normalize P pre-store
            if (tq < 3 || ln == 0) {
#pragma unroll
                for (int tk = 0; tk < 4; ++tk) {
                    uint2 u;
                    u.x = pk2(sacc[tk][j][0] * inv, sacc[tk][j][1] * inv);
                    u.y = pk2(sacc[tk][j][2] * inv, sacc[tk][j][3] * inv);
                    *(uint2*)(U + (16 * tq + ln) * USTR + 16 * tk + 4 * kg) = u;
                }
            }
        }
    }

    // PV: O^T[d][q] -> b64 ao writes into U cols [0,32) (q|k and P dead)
    s16x8 pf[4][2];
#pragma unroll
    for (int tq = 0; tq < 4; ++tq) {
        int pr = 16 * tq + ln; if (pr > 48) pr = 48;
#pragma unroll
        for (int ks = 0; ks < 2; ++ks)
            pf[tq][ks] = *(const s16x8*)(U + pr * USTR + 32 * ks + 8 * kg);
    }
#pragma unroll
    for (int td = 0; td < 2; ++td)
#pragma unroll
        for (int tq = 0; tq < 4; ++tq) {
            f32x4 a = {0.f, 0.f, 0.f, 0.f};
            a = __builtin_amdgcn_mfma_f32_16x16x32_bf16(vf[td][0], pf[tq][0], a, 0, 0, 0);
            a = __builtin_amdgcn_mfma_f32_16x16x32_bf16(vf[td][1], pf[tq][1], a, 0, 0, 0);
            const int q = 16 * tq + ln;
            if (q < 49) {
                uint2 u; u.x = pk2(a[0], a[1]); u.y = pk2(a[2], a[3]);
                *(uint2*)(U + q * USTR + 16 * td + 4 * kg) = u;
            }
        }
    __builtin_amdgcn_s_setprio(0);
    __syncthreads();                                 // the only barrier: ao complete

    // ---- Phase D: out-proj; wave g owns out-tiles {2g, 2g+1}:
    // 128 B contiguous per token per wave ----
    s16x8 af[4][3];
#pragma unroll
    for (int tt = 0; tt < 4; ++tt) {
        int tok = 16 * tt + ln; if (tok > 48) tok = 48;
#pragma unroll
        for (int ks = 0; ks < 3; ++ks)
            af[tt][ks] = *(const s16x8*)(s_u[ks] + tok * USTR + 8 * kg);
    }
#pragma unroll
    for (int j = 0; j < 2; ++j) {
        const int tc = 2 * g + j;
        s16x8 wf[3];
#pragma unroll
        for (int ks = 0; ks < 3; ++ks)
            wf[ks] = *(const s16x8*)(woT + (size_t)(16 * tc + ln) * 96 + 32 * ks + 8 * kg);
        const float4 bs = *(const float4*)(b_out + 16 * tc + 4 * kg);
#pragma unroll
        for (int tt = 0; tt < 4; ++tt) {
            f32x4 a = {bs.x, bs.y, bs.z, bs.w};      // bias as C-init
#pragma unroll
            for (int ks = 0; ks < 3; ++ks)
                a = __builtin_amdgcn_mfma_f32_16x16x32_bf16(wf[ks], af[tt][ks], a, 0, 0, 0);
            const int tok = 16 * tt + ln;
            if (tok < 49) {
                const int p = (tok * 37) >> 8;       // tok/7 for tok<=48
                const int q = tok - p * 7;
                float4 o; o.x = a[0]; o.y = a[1]; o.z = a[2]; o.w = a[3];
                *(float4*)(out + (base + (p * 8 + hh) * 56 + q * 8 + ww) * 96 + 16 * tc + 4 * kg) = o;
            }
        }
    }
}

// ---------------------------------------------------------------------------
// Fallback (round-1 fp32 monolith) if workspace is too small.
// ---------------------------------------------------------------------------
__global__ void winattn_fp32(const float* __restrict__ x,
                             const float* __restrict__ w_qkv,
                             const float* __restrict__ b_qkv,
                             const float* __restrict__ rel_pos,
                             const float* __restrict__ w_out,
                             const float* __restrict__ b_out,
                             float* __restrict__ out) {
    __shared__ float s_x[49][96];
    __shared__ float s_qkv[49][288];
    __shared__ float s_rel[3 * 169];
    const int t = threadIdx.x;
    const int blk = blockIdx.x;
    const int ww = blk & 7, hh = (blk >> 3) & 7, b = blk >> 6;
    for (int i = t; i < 3 * 169; i += 256) s_rel[i] = rel_pos[i];
    const float* xb = x + (size_t)b * 56 * 56 * 96;
    for (int i = t; i < 49 * 24; i += 256) {
        int tok = i / 24, ch4 = i % 24, p = tok / 7, q = tok % 7;
        float4 v = *(const float4*)(xb + (((p * 8 + hh) * 56) + (q * 8 + ww)) * 96 + ch4 * 4);
        *(float4*)(&s_x[tok][ch4 * 4]) = v;
    }
    __syncthreads();
    for (int u = t; u < 504; u += 256) {
        int cg = u % 72, rg = u / 72, col = cg * 4, r0 = rg * 7;
        float4 bq = *(const float4*)(b_qkv + col);
        float acc[7][4];
#pragma unroll
        for (int r = 0; r < 7; ++r) { acc[r][0]=bq.x; acc[r][1]=bq.y; acc[r][2]=bq.z; acc[r][3]=bq.w; }
        for (int k = 0; k < 96; k += 4) {
            float4 w0 = *(const float4*)(w_qkv + (size_t)(k+0)*288 + col);
            float4 w1 = *(const float4*)(w_qkv + (size_t)(k+1)*288 + col);
            float4 w2 = *(const float4*)(w_qkv + (size_t)(k+2)*288 + col);
            float4 w3 = *(const float4*)(w_qkv + (size_t)(k+3)*288 + col);
#pragma unroll
            for (int r = 0; r < 7; ++r) {
                float4 xv = *(const float4*)(&s_x[r0+r][k]);
                acc[r][0] += xv.x*w0.x + xv.y*w1.x + xv.z*w2.x + xv.w*w3.x;
                acc[r][1] += xv.x*w0.y + xv.y*w1.y + xv.z*w2.y + xv.w*w3.y;
                acc[r][2] += xv.x*w0.z + xv.y*w1.z + xv.z*w2.z + xv.w*w3.z;
                acc[r][3] += xv.x*w0.w + xv.y*w1.w + xv.z*w2.w + xv.w*w3.w;
            }
        }
#pragma unroll
        for (int r = 0; r < 7; ++r)
            *(float4*)(&s_qkv[r0+r][col]) = make_float4(acc[r][0],acc[r][1],acc[r][2],acc[r][3]);
    }
    __syncthreads();
    if (t < 147) {
        const int g = t / 49, qi = t - g * 49, pi = qi / 7, qq = qi - pi * 7;
        float qreg[32];
#pragma unroll
        for (int d = 0; d < 32; d += 4) {
            float4 v = *(const float4*)(&s_qkv[qi][g*32 + d]);
            qreg[d]=v.x*SCALE; qreg[d+1]=v.y*SCALE; qreg[d+2]=v.z*SCALE; qreg[d+3]=v.w*SCALE;
        }
        float sim[49]; float m = -1e30f;
        for (int j = 0; j < 49; ++j) {
            float a = 0.f;
            const float* kr = &s_qkv[j][96 + g*32];
#pragma unroll
            for (int d = 0; d < 32; d += 4) {
                float4 kv = *(const float4*)(kr + d);
                a += qreg[d]*kv.x + qreg[d+1]*kv.y + qreg[d+2]*kv.z + qreg[d+3]*kv.w;
            }
            int pj = j / 7, qj = j % 7;
            a += s_rel[g*169 + (pi-pj+6)*13 + (qq-qj+6)];
            sim[j] = a; m = fmaxf(m, a);
        }
        float s = 0.f;
        for (int j = 0; j < 49; ++j) { float e = __expf(sim[j]-m); sim[j]=e; s+=e; }
        float inv = 1.f/s;
        float o[32];
#pragma unroll
        for (int d = 0; d < 32; ++d) o[d] = 0.f;
        for (int j = 0; j < 49; ++j) {
            float p = sim[j];
            const float* vr = &s_qkv[j][192 + g*32];
#pragma unroll
            for (int d = 0; d < 32; d += 4) {
                float4 vv = *(const float4*)(vr + d);
                o[d] += p*vv.x; o[d+1] += p*vv.y; o[d+2] += p*vv.z; o[d+3] += p*vv.w;
            }
        }
#pragma unroll
        for (int d = 0; d < 32; d += 4)
            *(float4*)(&s_x[qi][g*32 + d]) = make_float4(o[d]*inv, o[d+1]*inv, o[d+2]*inv, o[d+3]*inv);
    }
    __syncthreads();
    for (int u = t; u < 336; u += 256) {
        int cg = u % 48, rg = u / 48, col = cg * 2, r0 = rg * 7;
        float b0 = b_out[col], b1 = b_out[col+1];
        float acc[7][2];
#pragma unroll
        for (int r = 0; r < 7; ++r) { acc[r][0]=b0; acc[r][1]=b1; }
        for (int k = 0; k < 96; k += 4) {
            float2 w0 = *(const float2*)(w_out + (size_t)(k+0)*96 + col);
            float2 w1 = *(const float2*)(w_out + (size_t)(k+1)*96 + col);
            float2 w2 = *(const float2*)(w_out + (size_t)(k+2)*96 + col);
            float2 w3 = *(const float2*)(w_out + (size_t)(k+3)*96 + col);
#pragma unroll
            for (int r = 0; r < 7; ++r) {
                float4 xv = *(const float4*)(&s_x[r0+r][k]);
                acc[r][0] += xv.x*w0.x + xv.y*w1.x + xv.z*w2.x + xv.w*w3.x;
                acc[r][1] += xv.x*w0.y + xv.y*w1.y + xv.z*w2.y + xv.w*w3.y;
            }
        }
#pragma unroll
        for (int r = 0; r < 7; ++r)
            *(float2*)(out + (size_t)(((b*56 + rg*8 + hh)*56) + r*8 + ww)*96 + col) =
                make_float2(acc[r][0], acc[r][1]);
    }
}

extern "C" void kernel_launch(void* const* d_in, const int* in_sizes, int n_in,
                              void* d_out, int out_size, void* d_ws, size_t ws_size,
                              hipStream_t stream) {
    const float* x       = (const float*)d_in[0];
    const float* w_qkv   = (const float*)d_in[1];
    const float* b_qkv   = (const float*)d_in[2];
    const float* rel_pos = (const float*)d_in[3];
    const float* w_out   = (const float*)d_in[4];
    const float* b_out   = (const float*)d_in[5];
    float* out = (float*)d_out;

    const size_t WQT_BYTES  = (size_t)288 * 96 * 2;     // 55,296
    const size_t WOT_BYTES  = (size_t)96 * 96 * 2;      // 18,432
    const size_t BIAS_BYTES = (size_t)3 * 49 * 64 * 4;  // 37,632

    if (ws_size >= WQT_BYTES + WOT_BYTES + BIAS_BYTES) {
        unsigned short* wqT = (unsigned short*)d_ws;
        unsigned short* woT = (unsigned short*)((char*)d_ws + WQT_BYTES);
        float* bias_exp     = (float*)((char*)d_ws + WQT_BYTES + WOT_BYTES);
        hipLaunchKernelGGL(k_prep,  dim3(181),  dim3(256), 0, stream,
                           w_qkv, w_out, rel_pos, wqT, woT, bias_exp);
        hipLaunchKernelGGL(k_fused, dim3(4096), dim3(192), 0, stream,
                           x, wqT, b_qkv, bias_exp, woT, b_out, out);
    } else {
        hipLaunchKernelGGL(winattn_fp32, dim3(4096), dim3(256), 0, stream,
                           x, w_qkv, b_qkv, rel_pos, w_out, b_out, out);
    }
}

// Round 8
// 191.271 us; speedup vs baseline: 1.4020x; 1.0455x over previous
//
#include <hip/hip_runtime.h>
#include <math.h>

#define SCALE 0.17677669529663687f   // 32^-0.5

typedef float f32x4 __attribute__((ext_vector_type(4)));
typedef short s16x8 __attribute__((ext_vector_type(8)));

__device__ __forceinline__ unsigned short f2bf(float f) {
    unsigned int u = __float_as_uint(f);
    u += 0x7fffu + ((u >> 16) & 1u);          // RNE
    return (unsigned short)(u >> 16);
}
__device__ __forceinline__ unsigned int pk2(float a, float b) {
    return (unsigned int)f2bf(a) | ((unsigned int)f2bf(b) << 16);
}

// ---------------------------------------------------------------------------
// K0: one-time prep.
//  - wqT[c][k] (288x96) bf16, Q-scale folded into first 96 cols
//  - woT[c][k] (96x96) bf16
//  - bias_exp[3][49][64] f32: rel-pos bias expanded dense so attention C-init
//    is one dwordx4 load. kt in [49,64) = 0 (masked post-MFMA).
// ---------------------------------------------------------------------------
__global__ void k_prep(const float* __restrict__ wq, const float* __restrict__ wo,
                       const float* __restrict__ rel_pos,
                       unsigned short* __restrict__ wqT, unsigned short* __restrict__ woT,
                       float* __restrict__ bias_exp) {
    int i = blockIdx.x * 256 + threadIdx.x;
    if (i < 27648) {
        int c = i / 96, k = i - c * 96;
        float w = wq[k * 288 + c];
        if (c < 96) w *= SCALE;                 // pre-scale q columns
        wqT[i] = f2bf(w);
    } else if (i < 36864) {
        int t = i - 27648;
        int c = t / 96, k = t - c * 96;
        woT[t] = f2bf(wo[k * 96 + c]);
    } else if (i < 36864 + 3 * 49 * 64) {
        int t = i - 36864;
        int g = t / 3136, r = t - g * 3136;
        int q = r >> 6, kt = r & 63;
        float v = 0.f;
        if (kt < 49) {
            int qp = q / 7, qq = q - qp * 7;
            int kp = kt / 7, kq = kt - kp * 7;
            v = rel_pos[g * 169 + (qp - kp + 6) * 13 + (qq - kq + 6)];
        }
        bias_exp[t] = v;
    }
}

// ---------------------------------------------------------------------------
// K1: fused per-window kernel, 192 threads (3 waves), wave g = head g
// end-to-end. Round-8: merge R3's winner (block-shared x staging: 1x
// conversion instead of 3x redundant, 6 instead of 24 global loads/lane,
// no L1 thrash) with R7's winner (V^T via ds_bpermute, 21 KB LDS):
//   - x staged bf16 ONCE into LDS, ALIASED over the U buffers (x-stage is
//     dead after xf register loads; barrier #2 protects the alias, exactly
//     R3's proven pattern) -> LDS stays 21,168 B, 7 blocks/CU
//   - Phase-D woT/b_out loads hoisted above the barrier (compiler cannot
//     hoist VMEM past s_barrier): their latency hides under the drain
// 3 barriers total; all other code identical to the verified R7 kernel.
// ---------------------------------------------------------------------------
#define XSTR 104   // x-stage row stride (shorts): 208 B, 16B-aligned
#define USTR  72   // U row stride (shorts): 144 B, 16B-aligned, 36 dwords (4 mod 32)

__global__ __launch_bounds__(192, 4) void k_fused(
        const float* __restrict__ x,
        const unsigned short* __restrict__ wqT,
        const float* __restrict__ b_qkv,
        const float* __restrict__ bias_exp,
        const unsigned short* __restrict__ woT,
        const float* __restrict__ b_out,
        float* __restrict__ out) {
    // 21168 B. Phase A: x bf16 [49][104] (5096 shorts) at offset 0.
    // After barrier 2: three per-head U buffers [49][72] (q|k -> P -> ao).
    __shared__ unsigned short s_mem[3 * 49 * USTR];

    const int tid  = threadIdx.x;
    const int g    = tid >> 6;         // wave index == head index (0..2)
    const int lane = tid & 63;
    const int ln   = lane & 15;
    const int kg   = lane >> 4;

    const int win = blockIdx.x;
    const int ww = win & 7, hh = (win >> 3) & 7, b = win >> 6;
    const size_t base = (size_t)b * 3136;

    // ---- Phase A: stage x window as bf16 (once per block) ----
    for (int i = tid; i < 1176; i += 192) {
        const int tok = i / 24, c = i - tok * 24;
        const int p = tok / 7, q = tok - p * 7;
        const float4 v = *(const float4*)(x + (base + (p * 8 + hh) * 56 + q * 8 + ww) * 96 + c * 4);
        uint2 u; u.x = pk2(v.x, v.y); u.y = pk2(v.z, v.w);
        *(uint2*)(s_mem + tok * XSTR + c * 4) = u;
    }
    __syncthreads();                                 // (1) x staged

    // x fragments into registers (x-stage region becomes U after barrier 2)
    s16x8 xf[4][3];
#pragma unroll
    for (int t = 0; t < 4; ++t) {
        int tok = 16 * t + ln; if (tok > 48) tok = 48;
#pragma unroll
        for (int ks = 0; ks < 3; ++ks)
            xf[t][ks] = *(const s16x8*)(s_mem + tok * XSTR + 32 * ks + 8 * kg);
    }
    __syncthreads();                                 // (2) all xf loaded; alias safe

    unsigned short* const U = s_mem + g * (49 * USTR);

    __builtin_amdgcn_s_setprio(1);                 // favor compute-phase waves

    // ---- Phase B: QKV GEMM for head g ----
    // q,k swapped: D[d][tok] -> b64 writes into [tok][d]; bias as C-init.
#pragma unroll
    for (int part = 0; part < 2; ++part) {           // 0:q (pre-scaled W), 1:k
#pragma unroll
        for (int tc = 0; tc < 2; ++tc) {
            const int col = part * 96 + g * 32 + 16 * tc + ln;
            s16x8 wf[3];
#pragma unroll
            for (int ks = 0; ks < 3; ++ks)
                wf[ks] = *(const s16x8*)(wqT + (size_t)col * 96 + 32 * ks + 8 * kg);
            const float4 bs = *(const float4*)(b_qkv + part * 96 + g * 32 + 16 * tc + 4 * kg);
            const float bm = part ? 1.0f : SCALE;
#pragma unroll
            for (int tt = 0; tt < 4; ++tt) {
                f32x4 a = {bs.x * bm, bs.y * bm, bs.z * bm, bs.w * bm};
#pragma unroll
                for (int ks = 0; ks < 3; ++ks)
                    a = __builtin_amdgcn_mfma_f32_16x16x32_bf16(wf[ks], xf[tt][ks], a, 0, 0, 0);
                if (tt < 3 || ln == 0) {             // token rows < 49 only
                    uint2 u; u.x = pk2(a[0], a[1]); u.y = pk2(a[2], a[3]);
                    *(uint2*)(U + (16 * tt + ln) * USTR + part * 40 + 16 * tc + 4 * kg) = u;
                }
            }
        }
    }
    // v non-swapped: D[tok][d] -> lane (ln,kg) holds V[d=16tc+ln][16tt+4kg..+3];
    // pack each granule to 2 bf16 dwords (registers, no LDS).
    int vpk01[2][4], vpk23[2][4];
#pragma unroll
    for (int tc = 0; tc < 2; ++tc) {
        const int col = 192 + g * 32 + 16 * tc + ln;
        s16x8 wf[3];
#pragma unroll
        for (int ks = 0; ks < 3; ++ks)
            wf[ks] = *(const s16x8*)(wqT + (size_t)col * 96 + 32 * ks + 8 * kg);
        const float bv = b_qkv[col];
#pragma unroll
        for (int tt = 0; tt < 4; ++tt) {
            f32x4 a = {bv, bv, bv, bv};
#pragma unroll
            for (int ks = 0; ks < 3; ++ks)
                a = __builtin_amdgcn_mfma_f32_16x16x32_bf16(xf[tt][ks], wf[ks], a, 0, 0, 0);
            vpk01[tc][tt] = (int)pk2(a[0], a[1]);
            vpk23[tc][tt] = (int)pk2(a[2], a[3]);
        }
    }
    // V^T fragments via cross-lane redistribution:
    // vf[td][ks](ln,kg)[e] = V^T[16td+ln][32ks+8kg+e], e=0..7.
    // Sources: lanes 16*kgp+ln, kgp in {2(kg&1), 2(kg&1)+1}; producer register
    // tt' = 2ks+(kg>>1) (lane-varying -> bpermute both, cndmask select).
    s16x8 vf[2][2];
    {
        const int addrA = 4 * (32 * (kg & 1) + ln);   // lane 16*2(kg&1)+ln
        const int addrB = addrA + 64;                 // lane +16
        const bool hi = (kg >> 1) != 0;
#pragma unroll
        for (int td = 0; td < 2; ++td)
#pragma unroll
            for (int ks = 0; ks < 2; ++ks) {
                const int d0a = __builtin_amdgcn_ds_bpermute(addrA, vpk01[td][2 * ks]);
                const int d0b = __builtin_amdgcn_ds_bpermute(addrA, vpk01[td][2 * ks + 1]);
                const int d1a = __builtin_amdgcn_ds_bpermute(addrA, vpk23[td][2 * ks]);
                const int d1b = __builtin_amdgcn_ds_bpermute(addrA, vpk23[td][2 * ks + 1]);
                const int d2a = __builtin_amdgcn_ds_bpermute(addrB, vpk01[td][2 * ks]);
                const int d2b = __builtin_amdgcn_ds_bpermute(addrB, vpk01[td][2 * ks + 1]);
                const int d3a = __builtin_amdgcn_ds_bpermute(addrB, vpk23[td][2 * ks]);
                const int d3b = __builtin_amdgcn_ds_bpermute(addrB, vpk23[td][2 * ks + 1]);
                uint4 u;
                u.x = (unsigned)(hi ? d0b : d0a);
                u.y = (unsigned)(hi ? d1b : d1a);
                u.z = (unsigned)(hi ? d2b : d2a);
                u.w = (unsigned)(hi ? d3b : d3a);
                vf[td][ks] = *(s16x8*)&u;
            }
    }

    // ---- Phase C: attention for head g (same-wave DS ordering, no barriers) ----
    s16x8 qf[4], kf[4];
#pragma unroll
    for (int t = 0; t < 4; ++t) {
        int tok = 16 * t + ln; if (tok > 48) tok = 48;
        qf[t] = *(const s16x8*)(U + tok * USTR + 8 * kg);
        kf[t] = *(const s16x8*)(U + tok * USTR + 40 + 8 * kg);
    }
    // Swapped QK^T in two tq-halves (sacc[4][2] = 32 VGPR peak).
#pragma unroll
    for (int th = 0; th < 2; ++th) {
        f32x4 sacc[4][2];
#pragma unroll
        for (int j = 0; j < 2; ++j) {
            const int tq = 2 * th + j;
            int qr = 16 * tq + ln; if (qr > 48) qr = 48;
            const float* brow = bias_exp + (g * 49 + qr) * 64;
#pragma unroll
            for (int tk = 0; tk < 4; ++tk) {
                const float4 bb = *(const float4*)(brow + 16 * tk + 4 * kg);
                f32x4 c = {bb.x, bb.y, bb.z, bb.w};
                sacc[tk][j] = __builtin_amdgcn_mfma_f32_16x16x32_bf16(kf[tk], qf[tq], c, 0, 0, 0);
            }
        }
        // mask kt >= 49 (tile 3: kt = 48 + 4kg + r)
#pragma unroll
        for (int j = 0; j < 2; ++j) {
            sacc[3][j][1] = -3e38f; sacc[3][j][2] = -3e38f; sacc[3][j][3] = -3e38f;
            if (kg) sacc[3][j][0] = -3e38f;
        }
        // softmax per q (r and tk in-lane, kg cross-lane)
#pragma unroll
        for (int j = 0; j < 2; ++j) {
            const int tq = 2 * th + j;
            float m0 = fmaxf(fmaxf(sacc[0][j][0], sacc[0][j][1]), fmaxf(sacc[0][j][2], sacc[0][j][3]));
            float m1 = fmaxf(fmaxf(sacc[1][j][0], sacc[1][j][1]), fmaxf(sacc[1][j][2], sacc[1][j][3]));
            float m2 = fmaxf(fmaxf(sacc[2][j][0], sacc[2][j][1]), fmaxf(sacc[2][j][2], sacc[2][j][3]));
            float m3 = fmaxf(fmaxf(sacc[3][j][0], sacc[3][j][1]), fmaxf(sacc[3][j][2], sacc[3][j][3]));
            float m = fmaxf(fmaxf(m0, m1), fmaxf(m2, m3));
            m = fmaxf(m, __shfl_xor(m, 16));
            m = fmaxf(m, __shfl_xor(m, 32));
            float s = 0.f;
#pragma unroll
            for (int tk = 0; tk < 4; ++tk)
#pragma unroll
                for (int r = 0; r < 4; ++r) {
                    const float e = __expf(sacc[tk][j][r] - m);
                    sacc[tk][j][r] = e; s += e;
                }
            s += __shfl_xor(s, 16);
            s += __shfl_xor(s, 32);
            const float inv = 1.0f / s;              // normalize P pre-store
            if (tq < 3 || ln == 0) {
#pragma unroll
                for (int tk = 0; tk < 4; ++tk) {
                    uint2 u;
                    u.x = pk2(sacc[tk][j][0] * inv, sacc[tk][j][1] * inv);
                    u.y = pk2(sacc[tk][j][2] * inv, sacc[tk][j][3] * inv);
                    *(uint2*)(U + (16 * tq + ln) * USTR + 16 * tk + 4 * kg) = u;
                }
            }
        }
    }

    // PV: O^T[d][q] -> b64 ao writes into U cols [0,32) (q|k and P dead)
    s16x8 pf[4][2];
#pragma unroll
    for (int tq = 0; tq < 4; ++tq) {
        int pr = 16 * tq + ln; if (pr > 48) pr = 48;
#pragma unroll
        for (int ks = 0; ks < 2; ++ks)
            pf[tq][ks] = *(const s16x8*)(U + pr * USTR + 32 * ks + 8 * kg);
    }
#pragma unroll
    for (int td = 0; td < 2; ++td)
#pragma unroll
        for (int tq = 0; tq < 4; ++tq) {
            f32x4 a = {0.f, 0.f, 0.f, 0.f};
            a = __builtin_amdgcn_mfma_f32_16x16x32_bf16(vf[td][0], pf[tq][0], a, 0, 0, 0);
            a = __builtin_amdgcn_mfma_f32_16x16x32_bf16(vf[td][1], pf[tq][1], a, 0, 0, 0);
            const int q = 16 * tq + ln;
            if (q < 49) {
                uint2 u; u.x = pk2(a[0], a[1]); u.y = pk2(a[2], a[3]);
                *(uint2*)(U + q * USTR + 16 * td + 4 * kg) = u;
            }
        }

    // Hoist Phase-D weight/bias loads ABOVE the barrier: compiler cannot move
    // VMEM past s_barrier; issuing here hides their latency under the drain.
    s16x8 wfo[2][3];
    float4 bso[2];
#pragma unroll
    for (int j = 0; j < 2; ++j) {
        const int tc = 2 * g + j;
#pragma unroll
        for (int ks = 0; ks < 3; ++ks)
            wfo[j][ks] = *(const s16x8*)(woT + (size_t)(16 * tc + ln) * 96 + 32 * ks + 8 * kg);
        bso[j] = *(const float4*)(b_out + 16 * tc + 4 * kg);
    }

    __builtin_amdgcn_s_setprio(0);
    __syncthreads();                                 // (3) ao complete across waves

    // ---- Phase D: out-proj; wave g owns out-tiles {2g, 2g+1}:
    // 128 B contiguous per token per wave ----
    s16x8 af[4][3];
#pragma unroll
    for (int tt = 0; tt < 4; ++tt) {
        int tok = 16 * tt + ln; if (tok > 48) tok = 48;
#pragma unroll
        for (int ks = 0; ks < 3; ++ks)
            af[tt][ks] = *(const s16x8*)(s_mem + ks * (49 * USTR) + tok * USTR + 8 * kg);
    }
#pragma unroll
    for (int j = 0; j < 2; ++j) {
        const int tc = 2 * g + j;
#pragma unroll
        for (int tt = 0; tt < 4; ++tt) {
            f32x4 a = {bso[j].x, bso[j].y, bso[j].z, bso[j].w};   // bias as C-init
#pragma unroll
            for (int ks = 0; ks < 3; ++ks)
                a = __builtin_amdgcn_mfma_f32_16x16x32_bf16(wfo[j][ks], af[tt][ks], a, 0, 0, 0);
            const int tok = 16 * tt + ln;
            if (tok < 49) {
                const int p = (tok * 37) >> 8;       // tok/7 for tok<=48
                const int q = tok - p * 7;
                float4 o; o.x = a[0]; o.y = a[1]; o.z = a[2]; o.w = a[3];
                *(float4*)(out + (base + (p * 8 + hh) * 56 + q * 8 + ww) * 96 + 16 * tc + 4 * kg) = o;
            }
        }
    }
}

// ---------------------------------------------------------------------------
// Fallback (round-1 fp32 monolith) if workspace is too small.
// ---------------------------------------------------------------------------
__global__ void winattn_fp32(const float* __restrict__ x,
                             const float* __restrict__ w_qkv,
                             const float* __restrict__ b_qkv,
                             const float* __restrict__ rel_pos,
                             const float* __restrict__ w_out,
                             const float* __restrict__ b_out,
                             float* __restrict__ out) {
    __shared__ float s_x[49][96];
    __shared__ float s_qkv[49][288];
    __shared__ float s_rel[3 * 169];
    const int t = threadIdx.x;
    const int blk = blockIdx.x;
    const int ww = blk & 7, hh = (blk >> 3) & 7, b = blk >> 6;
    for (int i = t; i < 3 * 169; i += 256) s_rel[i] = rel_pos[i];
    const float* xb = x + (size_t)b * 56 * 56 * 96;
    for (int i = t; i < 49 * 24; i += 256) {
        int tok = i / 24, ch4 = i % 24, p = tok / 7, q = tok % 7;
        float4 v = *(const float4*)(xb + (((p * 8 + hh) * 56) + (q * 8 + ww)) * 96 + ch4 * 4);
        *(float4*)(&s_x[tok][ch4 * 4]) = v;
    }
    __syncthreads();
    for (int u = t; u < 504; u += 256) {
        int cg = u % 72, rg = u / 72, col = cg * 4, r0 = rg * 7;
        float4 bq = *(const float4*)(b_qkv + col);
        float acc[7][4];
#pragma unroll
        for (int r = 0; r < 7; ++r) { acc[r][0]=bq.x; acc[r][1]=bq.y; acc[r][2]=bq.z; acc[r][3]=bq.w; }
        for (int k = 0; k < 96; k += 4) {
            float4 w0 = *(const float4*)(w_qkv + (size_t)(k+0)*288 + col);
            float4 w1 = *(const float4*)(w_qkv + (size_t)(k+1)*288 + col);
            float4 w2 = *(const float4*)(w_qkv + (size_t)(k+2)*288 + col);
            float4 w3 = *(const float4*)(w_qkv + (size_t)(k+3)*288 + col);
#pragma unroll
            for (int r = 0; r < 7; ++r) {
                float4 xv = *(const float4*)(&s_x[r0+r][k]);
                acc[r][0] += xv.x*w0.x + xv.y*w1.x + xv.z*w2.x + xv.w*w3.x;
                acc[r][1] += xv.x*w0.y + xv.y*w1.y + xv.z*w2.y + xv.w*w3.y;
                acc[r][2] += xv.x*w0.z + xv.y*w1.z + xv.z*w2.z + xv.w*w3.z;
                acc[r][3] += xv.x*w0.w + xv.y*w1.w + xv.z*w2.w + xv.w*w3.w;
            }
        }
#pragma unroll
        for (int r = 0; r < 7; ++r)
            *(float4*)(&s_qkv[r0+r][col]) = make_float4(acc[r][0],acc[r][1],acc[r][2],acc[r][3]);
    }
    __syncthreads();
    if (t < 147) {
        const int g = t / 49, qi = t - g * 49, pi = qi / 7, qq = qi - pi * 7;
        float qreg[32];
#pragma unroll
        for (int d = 0; d < 32; d += 4) {
            float4 v = *(const float4*)(&s_qkv[qi][g*32 + d]);
            qreg[d]=v.x*SCALE; qreg[d+1]=v.y*SCALE; qreg[d+2]=v.z*SCALE; qreg[d+3]=v.w*SCALE;
        }
        float sim[49]; float m = -1e30f;
        for (int j = 0; j < 49; ++j) {
            float a = 0.f;
            const float* kr = &s_qkv[j][96 + g*32];
#pragma unroll
            for (int d = 0; d < 32; d += 4) {
                float4 kv = *(const float4*)(kr + d);
                a += qreg[d]*kv.x + qreg[d+1]*kv.y + qreg[d+2]*kv.z + qreg[d+3]*kv.w;
            }
            int pj = j / 7, qj = j % 7;
            a += s_rel[g*169 + (pi-pj+6)*13 + (qq-qj+6)];
            sim[j] = a; m = fmaxf(m, a);
        }
        float s = 0.f;
        for (int j = 0; j < 49; ++j) { float e = __expf(sim[j]-m); sim[j]=e; s+=e; }
        float inv = 1.f/s;
        float o[32];
#pragma unroll
        for (int d = 0; d < 32; ++d) o[d] = 0.f;
        for (int j = 0; j < 49; ++j) {
            float p = sim[j];
            const float* vr = &s_qkv[j][192 + g*32];
#pragma unroll
            for (int d = 0; d < 32; d += 4) {
                float4 vv = *(const float4*)(vr + d);
                o[d] += p*vv.x; o[d+1] += p*vv.y; o[d+2] += p*vv.z; o[d+3] += p*vv.w;
            }
        }
#pragma unroll
        for (int d = 0; d < 32; d += 4)
            *(float4*)(&s_x[qi][g*32 + d]) = make_float4(o[d]*inv, o[d+1]*inv, o[d+2]*inv, o[d+3]*inv);
    }
    __syncthreads();
    for (int u = t; u < 336; u += 256) {
        int cg = u % 48, rg = u / 48, col = cg * 2, r0 = rg * 7;
        float b0 = b_out[col], b1 = b_out[col+1];
        float acc[7][2];
#pragma unroll
        for (int r = 0; r < 7; ++r) { acc[r][0]=b0; acc[r][1]=b1; }
        for (int k = 0; k < 96; k += 4) {
            float2 w0 = *(const float2*)(w_out + (size_t)(k+0)*96 + col);
            float2 w1 = *(const float2*)(w_out + (size_t)(k+1)*96 + col);
            float2 w2 = *(const float2*)(w_out + (size_t)(k+2)*96 + col);
            float2 w3 = *(const float2*)(w_out + (size_t)(k+3)*96 + col);
#pragma unroll
            for (int r = 0; r < 7; ++r) {
                float4 xv = *(const float4*)(&s_x[r0+r][k]);
                acc[r][0] += xv.x*w0.x + xv.y*w1.x + xv.z*w2.x + xv.w*w3.x;
                acc[r][1] += xv.x*w0.y + xv.y*w1.y + xv.z*w2.y + xv.w*w3.y;
            }
        }
#pragma unroll
        for (int r = 0; r < 7; ++r)
            *(float2*)(out + (size_t)(((b*56 + rg*8 + hh)*56) + r*8 + ww)*96 + col) =
                make_float2(acc[r][0], acc[r][1]);
    }
}

extern "C" void kernel_launch(void* const* d_in, const int* in_sizes, int n_in,
                              void* d_out, int out_size, void* d_ws, size_t ws_size,
                              hipStream_t stream) {
    const float* x       = (const float*)d_in[0];
    const float* w_qkv   = (const float*)d_in[1];
    const float* b_qkv   = (const float*)d_in[2];
    const float* rel_pos = (const float*)d_in[3];
    const float* w_out   = (const float*)d_in[4];
    const float* b_out   = (const float*)d_in[5];
    float* out = (float*)d_out;

    const size_t WQT_BYTES  = (size_t)288 * 96 * 2;     // 55,296
    const size_t WOT_BYTES  = (size_t)96 * 96 * 2;      // 18,432
    const size_t BIAS_BYTES = (size_t)3 * 49 * 64 * 4;  // 37,632

    if (ws_size >= WQT_BYTES + WOT_BYTES + BIAS_BYTES) {
        unsigned short* wqT = (unsigned short*)d_ws;
        unsigned short* woT = (unsigned short*)((char*)d_ws + WQT_BYTES);
        float* bias_exp     = (float*)((char*)d_ws + WQT_BYTES + WOT_BYTES);
        hipLaunchKernelGGL(k_prep,  dim3(181),  dim3(256), 0, stream,
                           w_qkv, w_out, rel_pos, wqT, woT, bias_exp);
        hipLaunchKernelGGL(k_fused, dim3(4096), dim3(192), 0, stream,
                           x, wqT, b_qkv, bias_exp, woT, b_out, out);
    } else {
        hipLaunchKernelGGL(winattn_fp32, dim3(4096), dim3(256), 0, stream,
                           x, w_qkv, b_qkv, rel_pos, w_out, b_out, out);
    }
}

// Round 9
// 185.958 us; speedup vs baseline: 1.4420x; 1.0286x over previous
//
#include <hip/hip_runtime.h>
#include <math.h>

#define SCALE 0.17677669529663687f   // 32^-0.5

typedef float f32x4 __attribute__((ext_vector_type(4)));
typedef short s16x8 __attribute__((ext_vector_type(8)));

__device__ __forceinline__ unsigned short f2bf(float f) {
    unsigned int u = __float_as_uint(f);
    u += 0x7fffu + ((u >> 16) & 1u);          // RNE
    return (unsigned short)(u >> 16);
}
__device__ __forceinline__ unsigned int pk2(float a, float b) {
    return (unsigned int)f2bf(a) | ((unsigned int)f2bf(b) << 16);
}

// ---------------------------------------------------------------------------
// K0: one-time prep -> LANE-MAJOR fragment layouts (all fragment loads in
// k_fused become one coalesced 1KB transaction instead of a 16-way scatter):
//  - wqF[(T*3+ks)*64 + lane][8] bf16: T=0..17 (16-col tiles of w_qkv^T),
//    lane=(kg*16+ln); element e = w_qkv[(32ks+8kg+e)*288 + 16T+ln],
//    Q-scale folded for T<6.
//  - woF[(T*3+ks)*64 + lane][8] bf16: T=0..5 over w_out.
//  - biasF[((g*4+tq)*4+tk)*64 + lane][4] f32: rel-pos bias with row clamp
//    (qr=min(16tq+ln,48)) and kt>=49 zero-pad baked in.
// ---------------------------------------------------------------------------
__global__ void k_prep(const float* __restrict__ wq, const float* __restrict__ wo,
                       const float* __restrict__ rel_pos,
                       unsigned short* __restrict__ wqF, unsigned short* __restrict__ woF,
                       float* __restrict__ biasF) {
    int i = blockIdx.x * 256 + threadIdx.x;
    if (i < 27648) {                       // wqF: 54 frags x 64 lanes x 8
        const int e = i & 7, lane = (i >> 3) & 63, fk = i >> 9;
        const int T = fk / 3, ks = fk - T * 3;
        const int ln = lane & 15, kg = lane >> 4;
        const int col = 16 * T + ln, k = 32 * ks + 8 * kg + e;
        float w = wq[k * 288 + col];
        if (T < 6) w *= SCALE;             // q columns pre-scaled
        wqF[i] = f2bf(w);
    } else if (i < 36864) {                // woF: 18 frags x 64 x 8
        const int t = i - 27648;
        const int e = t & 7, lane = (t >> 3) & 63, fk = t >> 9;
        const int T = fk / 3, ks = fk - T * 3;
        const int ln = lane & 15, kg = lane >> 4;
        woF[t] = f2bf(wo[(32 * ks + 8 * kg + e) * 96 + 16 * T + ln]);
    } else if (i < 49152) {                // biasF: 48 frags x 64 x 4
        const int t = i - 36864;
        const int e = t & 3, lane = (t >> 2) & 63, fid = t >> 8;
        const int g = fid >> 4, r = fid & 15;
        const int tq = r >> 2, tk = r & 3;
        const int ln = lane & 15, kg = lane >> 4;
        int qr = 16 * tq + ln; if (qr > 48) qr = 48;
        const int kt = 16 * tk + 4 * kg + e;
        float v = 0.f;
        if (kt < 49) {
            const int qp = qr / 7, qq = qr - qp * 7;
            const int kp = kt / 7, kq = kt - kp * 7;
            v = rel_pos[g * 169 + (qp - kp + 6) * 13 + (qq - kq + 6)];
        }
        biasF[t] = v;
    }
}

// ---------------------------------------------------------------------------
// K1: fused per-window kernel, 192 threads (3 waves), wave g = head g
// end-to-end. Round-9 = round-8 structure (block-shared x staging aliased
// over U, V^T via ds_bpermute, 3 barriers, 21 KB LDS) with ALL weight/bias
// fragment loads switched to the lane-major layouts above: each load is now
// base + frag*1024 + lane*16 -> single coalesced 1KB transaction (was a
// 16-segment L2 gather at the head of every phase's dependency chain).
// ---------------------------------------------------------------------------
#define XSTR 104   // x-stage row stride (shorts): 208 B, 16B-aligned
#define USTR  72   // U row stride (shorts): 144 B, 16B-aligned, 36 dwords (4 mod 32)

__global__ __launch_bounds__(192, 4) void k_fused(
        const float* __restrict__ x,
        const unsigned short* __restrict__ wqF,
        const float* __restrict__ b_qkv,
        const float* __restrict__ biasF,
        const unsigned short* __restrict__ woF,
        const float* __restrict__ b_out,
        float* __restrict__ out) {
    // 21168 B. Phase A: x bf16 [49][104] at offset 0.
    // After barrier 2: three per-head U buffers [49][72] (q|k -> P -> ao).
    __shared__ unsigned short s_mem[3 * 49 * USTR];

    const int tid  = threadIdx.x;
    const int g    = tid >> 6;         // wave index == head index (0..2)
    const int lane = tid & 63;
    const int ln   = lane & 15;
    const int kg   = lane >> 4;

    const int win = blockIdx.x;
    const int ww = win & 7, hh = (win >> 3) & 7, b = win >> 6;
    const size_t base = (size_t)b * 3136;

    // ---- Phase A: stage x window as bf16 (once per block) ----
    for (int i = tid; i < 1176; i += 192) {
        const int tok = i / 24, c = i - tok * 24;
        const int p = tok / 7, q = tok - p * 7;
        const float4 v = *(const float4*)(x + (base + (p * 8 + hh) * 56 + q * 8 + ww) * 96 + c * 4);
        uint2 u; u.x = pk2(v.x, v.y); u.y = pk2(v.z, v.w);
        *(uint2*)(s_mem + tok * XSTR + c * 4) = u;
    }
    __syncthreads();                                 // (1) x staged

    // x fragments into registers (x-stage region becomes U after barrier 2)
    s16x8 xf[4][3];
#pragma unroll
    for (int t = 0; t < 4; ++t) {
        int tok = 16 * t + ln; if (tok > 48) tok = 48;
#pragma unroll
        for (int ks = 0; ks < 3; ++ks)
            xf[t][ks] = *(const s16x8*)(s_mem + tok * XSTR + 32 * ks + 8 * kg);
    }
    __syncthreads();                                 // (2) all xf loaded; alias safe

    unsigned short* const U = s_mem + g * (49 * USTR);

    __builtin_amdgcn_s_setprio(1);                 // favor compute-phase waves

    // ---- Phase B: QKV GEMM for head g ----
    // q,k swapped: D[d][tok] -> b64 writes into [tok][d]; bias as C-init.
#pragma unroll
    for (int part = 0; part < 2; ++part) {           // 0:q (pre-scaled W), 1:k
#pragma unroll
        for (int tc = 0; tc < 2; ++tc) {
            const int T = part * 6 + 2 * g + tc;     // col tile in wqF
            s16x8 wf[3];
#pragma unroll
            for (int ks = 0; ks < 3; ++ks)
                wf[ks] = *(const s16x8*)(wqF + ((size_t)(T * 3 + ks) * 64 + lane) * 8);
            const float4 bs = *(const float4*)(b_qkv + part * 96 + g * 32 + 16 * tc + 4 * kg);
            const float bm = part ? 1.0f : SCALE;
#pragma unroll
            for (int tt = 0; tt < 4; ++tt) {
                f32x4 a = {bs.x * bm, bs.y * bm, bs.z * bm, bs.w * bm};
#pragma unroll
                for (int ks = 0; ks < 3; ++ks)
                    a = __builtin_amdgcn_mfma_f32_16x16x32_bf16(wf[ks], xf[tt][ks], a, 0, 0, 0);
                if (tt < 3 || ln == 0) {             // token rows < 49 only
                    uint2 u; u.x = pk2(a[0], a[1]); u.y = pk2(a[2], a[3]);
                    *(uint2*)(U + (16 * tt + ln) * USTR + part * 40 + 16 * tc + 4 * kg) = u;
                }
            }
        }
    }
    // v non-swapped: D[tok][d] -> lane (ln,kg) holds V[d=16tc+ln][16tt+4kg..+3];
    // pack each granule to 2 bf16 dwords (registers, no LDS).
    int vpk01[2][4], vpk23[2][4];
#pragma unroll
    for (int tc = 0; tc < 2; ++tc) {
        const int T = 12 + 2 * g + tc;               // v col tile in wqF
        s16x8 wf[3];
#pragma unroll
        for (int ks = 0; ks < 3; ++ks)
            wf[ks] = *(const s16x8*)(wqF + ((size_t)(T * 3 + ks) * 64 + lane) * 8);
        const float bv = b_qkv[192 + g * 32 + 16 * tc + ln];
#pragma unroll
        for (int tt = 0; tt < 4; ++tt) {
            f32x4 a = {bv, bv, bv, bv};
#pragma unroll
            for (int ks = 0; ks < 3; ++ks)
                a = __builtin_amdgcn_mfma_f32_16x16x32_bf16(xf[tt][ks], wf[ks], a, 0, 0, 0);
            vpk01[tc][tt] = (int)pk2(a[0], a[1]);
            vpk23[tc][tt] = (int)pk2(a[2], a[3]);
        }
    }
    // V^T fragments via cross-lane redistribution:
    // vf[td][ks](ln,kg)[e] = V^T[16td+ln][32ks+8kg+e], e=0..7.
    s16x8 vf[2][2];
    {
        const int addrA = 4 * (32 * (kg & 1) + ln);   // lane 16*2(kg&1)+ln
        const int addrB = addrA + 64;                 // lane +16
        const bool hi = (kg >> 1) != 0;
#pragma unroll
        for (int td = 0; td < 2; ++td)
#pragma unroll
            for (int ks = 0; ks < 2; ++ks) {
                const int d0a = __builtin_amdgcn_ds_bpermute(addrA, vpk01[td][2 * ks]);
                const int d0b = __builtin_amdgcn_ds_bpermute(addrA, vpk01[td][2 * ks + 1]);
                const int d1a = __builtin_amdgcn_ds_bpermute(addrA, vpk23[td][2 * ks]);
                const int d1b = __builtin_amdgcn_ds_bpermute(addrA, vpk23[td][2 * ks + 1]);
                const int d2a = __builtin_amdgcn_ds_bpermute(addrB, vpk01[td][2 * ks]);
                const int d2b = __builtin_amdgcn_ds_bpermute(addrB, vpk01[td][2 * ks + 1]);
                const int d3a = __builtin_amdgcn_ds_bpermute(addrB, vpk23[td][2 * ks]);
                const int d3b = __builtin_amdgcn_ds_bpermute(addrB, vpk23[td][2 * ks + 1]);
                uint4 u;
                u.x = (unsigned)(hi ? d0b : d0a);
                u.y = (unsigned)(hi ? d1b : d1a);
                u.z = (unsigned)(hi ? d2b : d2a);
                u.w = (unsigned)(hi ? d3b : d3a);
                vf[td][ks] = *(s16x8*)&u;
            }
    }

    // ---- Phase C: attention for head g (same-wave DS ordering, no barriers) ----
    s16x8 qf[4], kf[4];
#pragma unroll
    for (int t = 0; t < 4; ++t) {
        int tok = 16 * t + ln; if (tok > 48) tok = 48;
        qf[t] = *(const s16x8*)(U + tok * USTR + 8 * kg);
        kf[t] = *(const s16x8*)(U + tok * USTR + 40 + 8 * kg);
    }
    // Swapped QK^T in two tq-halves (sacc[4][2] = 32 VGPR peak).
#pragma unroll
    for (int th = 0; th < 2; ++th) {
        f32x4 sacc[4][2];
#pragma unroll
        for (int j = 0; j < 2; ++j) {
            const int tq = 2 * th + j;
#pragma unroll
            for (int tk = 0; tk < 4; ++tk) {
                const float4 bb = *(const float4*)(biasF +
                        ((size_t)((g * 4 + tq) * 4 + tk) * 64 + lane) * 4);
                f32x4 c = {bb.x, bb.y, bb.z, bb.w};
                sacc[tk][j] = __builtin_amdgcn_mfma_f32_16x16x32_bf16(kf[tk], qf[tq], c, 0, 0, 0);
            }
        }
        // mask kt >= 49 (tile 3: kt = 48 + 4kg + r)
#pragma unroll
        for (int j = 0; j < 2; ++j) {
            sacc[3][j][1] = -3e38f; sacc[3][j][2] = -3e38f; sacc[3][j][3] = -3e38f;
            if (kg) sacc[3][j][0] = -3e38f;
        }
        // softmax per q (r and tk in-lane, kg cross-lane)
#pragma unroll
        for (int j = 0; j < 2; ++j) {
            const int tq = 2 * th + j;
            float m0 = fmaxf(fmaxf(sacc[0][j][0], sacc[0][j][1]), fmaxf(sacc[0][j][2], sacc[0][j][3]));
            float m1 = fmaxf(fmaxf(sacc[1][j][0], sacc[1][j][1]), fmaxf(sacc[1][j][2], sacc[1][j][3]));
            float m2 = fmaxf(fmaxf(sacc[2][j][0], sacc[2][j][1]), fmaxf(sacc[2][j][2], sacc[2][j][3]));
            float m3 = fmaxf(fmaxf(sacc[3][j][0], sacc[3][j][1]), fmaxf(sacc[3][j][2], sacc[3][j][3]));
            float m = fmaxf(fmaxf(m0, m1), fmaxf(m2, m3));
            m = fmaxf(m, __shfl_xor(m, 16));
            m = fmaxf(m, __shfl_xor(m, 32));
            float s = 0.f;
#pragma unroll
            for (int tk = 0; tk < 4; ++tk)
#pragma unroll
                for (int r = 0; r < 4; ++r) {
                    const float e = __expf(sacc[tk][j][r] - m);
                    sacc[tk][j][r] = e; s += e;
                }
            s += __shfl_xor(s, 16);
            s += __shfl_xor(s, 32);
            const float inv = 1.0f / s;              // normalize P pre-store
            if (tq < 3 || ln == 0) {
#pragma unroll
                for (int tk = 0; tk < 4; ++tk) {
                    uint2 u;
                    u.x = pk2(sacc[tk][j][0] * inv, sacc[tk][j][1] * inv);
                    u.y = pk2(sacc[tk][j][2] * inv, sacc[tk][j][3] * inv);
                    *(uint2*)(U + (16 * tq + ln) * USTR + 16 * tk + 4 * kg) = u;
                }
            }
        }
    }

    // PV: O^T[d][q] -> b64 ao writes into U cols [0,32) (q|k and P dead)
    s16x8 pf[4][2];
#pragma unroll
    for (int tq = 0; tq < 4; ++tq) {
        int pr = 16 * tq + ln; if (pr > 48) pr = 48;
#pragma unroll
        for (int ks = 0; ks < 2; ++ks)
            pf[tq][ks] = *(const s16x8*)(U + pr * USTR + 32 * ks + 8 * kg);
    }
#pragma unroll
    for (int td = 0; td < 2; ++td)
#pragma unroll
        for (int tq = 0; tq < 4; ++tq) {
            f32x4 a = {0.f, 0.f, 0.f, 0.f};
            a = __builtin_amdgcn_mfma_f32_16x16x32_bf16(vf[td][0], pf[tq][0], a, 0, 0, 0);
            a = __builtin_amdgcn_mfma_f32_16x16x32_bf16(vf[td][1], pf[tq][1], a, 0, 0, 0);
            const int q = 16 * tq + ln;
            if (q < 49) {
                uint2 u; u.x = pk2(a[0], a[1]); u.y = pk2(a[2], a[3]);
                *(uint2*)(U + q * USTR + 16 * td + 4 * kg) = u;
            }
        }

    // Hoist Phase-D weight/bias loads ABOVE the barrier (latency hides under
    // the drain); coalesced lane-major layout.
    s16x8 wfo[2][3];
    float4 bso[2];
#pragma unroll
    for (int j = 0; j < 2; ++j) {
        const int T2 = 2 * g + j;
#pragma unroll
        for (int ks = 0; ks < 3; ++ks)
            wfo[j][ks] = *(const s16x8*)(woF + ((size_t)(T2 * 3 + ks) * 64 + lane) * 8);
        bso[j] = *(const float4*)(b_out + 16 * T2 + 4 * kg);
    }

    __builtin_amdgcn_s_setprio(0);
    __syncthreads();                                 // (3) ao complete across waves

    // ---- Phase D: out-proj; wave g owns out-tiles {2g, 2g+1}:
    // 128 B contiguous per token per wave ----
    s16x8 af[4][3];
#pragma unroll
    for (int tt = 0; tt < 4; ++tt) {
        int tok = 16 * tt + ln; if (tok > 48) tok = 48;
#pragma unroll
        for (int ks = 0; ks < 3; ++ks)
            af[tt][ks] = *(const s16x8*)(s_mem + ks * (49 * USTR) + tok * USTR + 8 * kg);
    }
#pragma unroll
    for (int j = 0; j < 2; ++j) {
        const int tc = 2 * g + j;
#pragma unroll
        for (int tt = 0; tt < 4; ++tt) {
            f32x4 a = {bso[j].x, bso[j].y, bso[j].z, bso[j].w};   // bias as C-init
#pragma unroll
            for (int ks = 0; ks < 3; ++ks)
                a = __builtin_amdgcn_mfma_f32_16x16x32_bf16(wfo[j][ks], af[tt][ks], a, 0, 0, 0);
            const int tok = 16 * tt + ln;
            if (tok < 49) {
                const int p = (tok * 37) >> 8;       // tok/7 for tok<=48
                const int q = tok - p * 7;
                float4 o; o.x = a[0]; o.y = a[1]; o.z = a[2]; o.w = a[3];
                *(float4*)(out + (base + (p * 8 + hh) * 56 + q * 8 + ww) * 96 + 16 * tc + 4 * kg) = o;
            }
        }
    }
}

// ---------------------------------------------------------------------------
// Fallback (round-1 fp32 monolith) if workspace is too small.
// ---------------------------------------------------------------------------
__global__ void winattn_fp32(const float* __restrict__ x,
                             const float* __restrict__ w_qkv,
                             const float* __restrict__ b_qkv,
                             const float* __restrict__ rel_pos,
                             const float* __restrict__ w_out,
                             const float* __restrict__ b_out,
                             float* __restrict__ out) {
    __shared__ float s_x[49][96];
    __shared__ float s_qkv[49][288];
    __shared__ float s_rel[3 * 169];
    const int t = threadIdx.x;
    const int blk = blockIdx.x;
    const int ww = blk & 7, hh = (blk >> 3) & 7, b = blk >> 6;
    for (int i = t; i < 3 * 169; i += 256) s_rel[i] = rel_pos[i];
    const float* xb = x + (size_t)b * 56 * 56 * 96;
    for (int i = t; i < 49 * 24; i += 256) {
        int tok = i / 24, ch4 = i % 24, p = tok / 7, q = tok % 7;
        float4 v = *(const float4*)(xb + (((p * 8 + hh) * 56) + (q * 8 + ww)) * 96 + ch4 * 4);
        *(float4*)(&s_x[tok][ch4 * 4]) = v;
    }
    __syncthreads();
    for (int u = t; u < 504; u += 256) {
        int cg = u % 72, rg = u / 72, col = cg * 4, r0 = rg * 7;
        float4 bq = *(const float4*)(b_qkv + col);
        float acc[7][4];
#pragma unroll
        for (int r = 0; r < 7; ++r) { acc[r][0]=bq.x; acc[r][1]=bq.y; acc[r][2]=bq.z; acc[r][3]=bq.w; }
        for (int k = 0; k < 96; k += 4) {
            float4 w0 = *(const float4*)(w_qkv + (size_t)(k+0)*288 + col);
            float4 w1 = *(const float4*)(w_qkv + (size_t)(k+1)*288 + col);
            float4 w2 = *(const float4*)(w_qkv + (size_t)(k+2)*288 + col);
            float4 w3 = *(const float4*)(w_qkv + (size_t)(k+3)*288 + col);
#pragma unroll
            for (int r = 0; r < 7; ++r) {
                float4 xv = *(const float4*)(&s_x[r0+r][k]);
                acc[r][0] += xv.x*w0.x + xv.y*w1.x + xv.z*w2.x + xv.w*w3.x;
                acc[r][1] += xv.x*w0.y + xv.y*w1.y + xv.z*w2.y + xv.w*w3.y;
                acc[r][2] += xv.x*w0.z + xv.y*w1.z + xv.z*w2.z + xv.w*w3.z;
                acc[r][3] += xv.x*w0.w + xv.y*w1.w + xv.z*w2.w + xv.w*w3.w;
            }
        }
#pragma unroll
        for (int r = 0; r < 7; ++r)
            *(float4*)(&s_qkv[r0+r][col]) = make_float4(acc[r][0],acc[r][1],acc[r][2],acc[r][3]);
    }
    __syncthreads();
    if (t < 147) {
        const int g = t / 49, qi = t - g * 49, pi = qi / 7, qq = qi - pi * 7;
        float qreg[32];
#pragma unroll
        for (int d = 0; d < 32; d += 4) {
            float4 v = *(const float4*)(&s_qkv[qi][g*32 + d]);
            qreg[d]=v.x*SCALE; qreg[d+1]=v.y*SCALE; qreg[d+2]=v.z*SCALE; qreg[d+3]=v.w*SCALE;
        }
        float sim[49]; float m = -1e30f;
        for (int j = 0; j < 49; ++j) {
            float a = 0.f;
            const float* kr = &s_qkv[j][96 + g*32];
#pragma unroll
            for (int d = 0; d < 32; d += 4) {
                float4 kv = *(const float4*)(kr + d);
                a += qreg[d]*kv.x + qreg[d+1]*kv.y + qreg[d+2]*kv.z + qreg[d+3]*kv.w;
            }
            int pj = j / 7, qj = j % 7;
            a += s_rel[g*169 + (pi-pj+6)*13 + (qq-qj+6)];
            sim[j] = a; m = fmaxf(m, a);
        }
        float s = 0.f;
        for (int j = 0; j < 49; ++j) { float e = __expf(sim[j]-m); sim[j]=e; s+=e; }
        float inv = 1.f/s;
        float o[32];
#pragma unroll
        for (int d = 0; d < 32; ++d) o[d] = 0.f;
        for (int j = 0; j < 49; ++j) {
            float p = sim[j];
            const float* vr = &s_qkv[j][192 + g*32];
#pragma unroll
            for (int d = 0; d < 32; d += 4) {
                float4 vv = *(const float4*)(vr + d);
                o[d] += p*vv.x; o[d+1] += p*vv.y; o[d+2] += p*vv.z; o[d+3] += p*vv.w;
            }
        }
#pragma unroll
        for (int d = 0; d < 32; d += 4)
            *(float4*)(&s_x[qi][g*32 + d]) = make_float4(o[d]*inv, o[d+1]*inv, o[d+2]*inv, o[d+3]*inv);
    }
    __syncthreads();
    for (int u = t; u < 336; u += 256) {
        int cg = u % 48, rg = u / 48, col = cg * 2, r0 = rg * 7;
        float b0 = b_out[col], b1 = b_out[col+1];
        float acc[7][2];
#pragma unroll
        for (int r = 0; r < 7; ++r) { acc[r][0]=b0; acc[r][1]=b1; }
        for (int k = 0; k < 96; k += 4) {
            float2 w0 = *(const float2*)(w_out + (size_t)(k+0)*96 + col);
            float2 w1 = *(const float2*)(w_out + (size_t)(k+1)*96 + col);
            float2 w2 = *(const float2*)(w_out + (size_t)(k+2)*96 + col);
            float2 w3 = *(const float2*)(w_out + (size_t)(k+3)*96 + col);
#pragma unroll
            for (int r = 0; r < 7; ++r) {
                float4 xv = *(const float4*)(&s_x[r0+r][k]);
                acc[r][0] += xv.x*w0.x + xv.y*w1.x + xv.z*w2.x + xv.w*w3.x;
                acc[r][1] += xv.x*w0.y + xv.y*w1.y + xv.z*w2.y + xv.w*w3.y;
            }
        }
#pragma unroll
        for (int r = 0; r < 7; ++r)
            *(float2*)(out + (size_t)(((b*56 + rg*8 + hh)*56) + r*8 + ww)*96 + col) =
                make_float2(acc[r][0], acc[r][1]);
    }
}

extern "C" void kernel_launch(void* const* d_in, const int* in_sizes, int n_in,
                              void* d_out, int out_size, void* d_ws, size_t ws_size,
                              hipStream_t stream) {
    const float* x       = (const float*)d_in[0];
    const float* w_qkv   = (const float*)d_in[1];
    const float* b_qkv   = (const float*)d_in[2];
    const float* rel_pos = (const float*)d_in[3];
    const float* w_out   = (const float*)d_in[4];
    const float* b_out   = (const float*)d_in[5];
    float* out = (float*)d_out;

    const size_t WQF_BYTES  = (size_t)288 * 96 * 2;     // 55,296
    const size_t WOF_BYTES  = (size_t)96 * 96 * 2;      // 18,432
    const size_t BIAS_BYTES = (size_t)48 * 64 * 4 * 4;  // 49,152

    if (ws_size >= WQF_BYTES + WOF_BYTES + BIAS_BYTES) {
        unsigned short* wqF = (unsigned short*)d_ws;
        unsigned short* woF = (unsigned short*)((char*)d_ws + WQF_BYTES);
        float* biasF        = (float*)((char*)d_ws + WQF_BYTES + WOF_BYTES);
        hipLaunchKernelGGL(k_prep,  dim3(192),  dim3(256), 0, stream,
                           w_qkv, w_out, rel_pos, wqF, woF, biasF);
        hipLaunchKernelGGL(k_fused, dim3(4096), dim3(192), 0, stream,
                           x, wqF, b_qkv, biasF, woF, b_out, out);
    } else {
        hipLaunchKernelGGL(winattn_fp32, dim3(4096), dim3(256), 0, stream,
                           x, w_qkv, b_qkv, rel_pos, w_out, b_out, out);
    }
}